// Round 10
// baseline (326.076 us; speedup 1.0000x reference)
//
#include <hip/hip_runtime.h>
#include <hip/hip_bf16.h>

typedef __bf16 bf16_t;
typedef __bf16 bf16x4 __attribute__((ext_vector_type(4)));
typedef __bf16 bf16x8 __attribute__((ext_vector_type(8)));
typedef float f32x4 __attribute__((ext_vector_type(4)));

typedef __attribute__((address_space(1))) unsigned char glob_u8;
typedef __attribute__((address_space(3))) unsigned char lds_u8;

__device__ __forceinline__ void load_lds16(const void* g, void* l) {
    __builtin_amdgcn_global_load_lds((glob_u8*)g, (lds_u8*)l, 16, 0, 0);
}

// ---------------------------------------------------------------------------
// prep1: maskflags (blocks 0..2047) + qkv weight transposes (2048..2815)
//        + OPTIONAL A f32->bf16 pre-convert (blocks 2816..4351, 512/z)
// NOTE: woT / inter-head transposes are NOT here -- they live in the K region
// of qkvb and may only be written after flash consumed K (prep2, below).
// Round-8's merge of prep2 into prep1 clobbered them -> absmax 3.75.
// ---------------------------------------------------------------------------
__global__ void prep1_kernel(const int* __restrict__ mask, int* __restrict__ flags,
                             const float* __restrict__ wq, const float* __restrict__ wk,
                             const float* __restrict__ wv, bf16_t* __restrict__ wqkvT,
                             const float* __restrict__ aq, const float* __restrict__ ak,
                             const float* __restrict__ av, bf16_t* __restrict__ abf)
{
    const int bid = blockIdx.x, t = threadIdx.x;
    if (bid < 2048) {
        int b = bid >> 10, qt = (bid >> 5) & 31, kt = bid & 31;
        int ok = 1;
#pragma unroll
        for (int i = 0; i < 16; i++) {
            int e = t + i * 256; int r = e >> 6, c = e & 63;
            ok &= (mask[((size_t)b * 2048 + qt * 64 + r) * 2048 + kt * 64 + c] != 0) ? 1 : 0;
        }
        ok = __syncthreads_and(ok);
        if (t == 0) flags[bid] = ok;
    } else if (bid < 2816) {
        __shared__ bf16_t tile[64][65];
        int idx = bid - 2048;
        int z = idx >> 8, rem = idx & 255;
        const float* src = (z == 0) ? wq : (z == 1) ? wk : wv;
        bf16_t* dst = wqkvT + (size_t)z * 1048576;
        int rB = (rem >> 4) * 64, cB = (rem & 15) * 64;
#pragma unroll
        for (int i = 0; i < 16; i++) {
            int e = t + i * 256; int r = e >> 6, c = e & 63;
            tile[r][c] = (bf16_t)src[(size_t)(rB + r) * 1024 + cB + c];
        }
        __syncthreads();
#pragma unroll
        for (int i = 0; i < 16; i++) {
            int e = t + i * 256; int r = e >> 6, c = e & 63;
            dst[(size_t)(cB + r) * 1024 + rB + c] = tile[c][r];
        }
    } else {
        // A pre-convert: 1536 blocks, each 256 thr x 32 elems = 8192 elems.
        int idx = bid - 2816;                 // 0..1535
        int z = idx >> 9, seg = idx & 511;    // 512 blocks per z
        const float* src = (z == 0) ? aq : (z == 1) ? ak : av;
        bf16_t* dst = abf + (size_t)z * 4194304;
        size_t base = (size_t)seg * 8192 + (size_t)t * 32;
#pragma unroll
        for (int j = 0; j < 4; j++) {         // 4 x (8 f32 -> bf16x8)
            f32x4 u = *(const f32x4*)(src + base + j * 8);
            f32x4 v = *(const f32x4*)(src + base + j * 8 + 4);
            bf16x8 o;
            o[0] = (bf16_t)u[0]; o[1] = (bf16_t)u[1];
            o[2] = (bf16_t)u[2]; o[3] = (bf16_t)u[3];
            o[4] = (bf16_t)v[0]; o[5] = (bf16_t)v[1];
            o[6] = (bf16_t)v[2]; o[7] = (bf16_t)v[3];
            *(bf16x8*)(dst + base + j * 8) = o;
        }
    }
}

// ---------------------------------------------------------------------------
// prep2: wo transpose (blocks 0..255) + small inter-head weight transposes.
// MUST run after flash_kernel: woT/whqT live in the (then-dead) K region.
// ---------------------------------------------------------------------------
__global__ void prep2_kernel(const float* __restrict__ wo, bf16_t* __restrict__ woT,
                             const float* __restrict__ s0, const float* __restrict__ s1,
                             const float* __restrict__ s2,
                             bf16_t* __restrict__ d0, bf16_t* __restrict__ d1, bf16_t* __restrict__ d2)
{
    const int bid = blockIdx.x, t = threadIdx.x;
    if (bid < 256) {
        __shared__ bf16_t tile[64][65];
        int rB = (bid >> 4) * 64, cB = (bid & 15) * 64;
#pragma unroll
        for (int i = 0; i < 16; i++) {
            int e = t + i * 256; int r = e >> 6, c = e & 63;
            tile[r][c] = (bf16_t)wo[(size_t)(rB + r) * 1024 + cB + c];
        }
        __syncthreads();
#pragma unroll
        for (int i = 0; i < 16; i++) {
            int e = t + i * 256; int r = e >> 6, c = e & 63;
            woT[(size_t)(cB + r) * 1024 + rB + c] = tile[c][r];
        }
    } else {
        int z = bid - 256;
        const float* src = (z == 0) ? s0 : (z == 1) ? s1 : s2;
        bf16_t* dst = (z == 0) ? d0 : (z == 1) ? d1 : d2;
#pragma unroll
        for (int i = 0; i < 16; i++) {
            int e = t + i * 256; int r = e >> 6, c = e & 63;
            dst[c * 64 + r] = (bf16_t)src[r * 64 + c];
        }
    }
}

// ---------------------------------------------------------------------------
// QKV GEMM v7: round-0 v1 structure (128x128 tile, register staging, GS=40,
// single-buffered, grid (32,8,3)). BF16A=true stages A from the pre-converted
// bf16 copy; false is the exact f32 fallback. Same LDS image bit-for-bit.
// ---------------------------------------------------------------------------
#define GS 40   // GEMM LDS row stride (bf16 elems) for a 32-wide K tile

template<bool BF16A>
__global__ __launch_bounds__(256, 2) void gemm_qkv_t(
    const float* __restrict__ Aq, const float* __restrict__ Ak, const float* __restrict__ Av,
    const bf16_t* __restrict__ Abf,
    const bf16_t* __restrict__ WT,
    const float* __restrict__ bq, const float* __restrict__ bk, const float* __restrict__ bv,
    bf16_t* __restrict__ outbase)
{
    __shared__ bf16_t As[128 * GS];
    __shared__ bf16_t Bs[128 * GS];
    const int z = blockIdx.z;
    const float* A    = (z == 0) ? Aq : (z == 1) ? Ak : Av;
    const bf16_t* Ab  = Abf + (size_t)z * 4194304;
    const bf16_t* Bt  = WT + (size_t)z * 1048576;
    const float* bia  = (z == 0) ? bq : (z == 1) ? bk : bv;
    bf16_t* out = outbase + (size_t)z * 4194304;

    const int t = threadIdx.x;
    const int w = t >> 6, lane = t & 63;
    const int lane15 = lane & 15, quad = lane >> 4;
    const int wr = w >> 1, wc = w & 1;
    const int rowBase = blockIdx.x * 128, colBase = blockIdx.y * 128;

    const int ar = t >> 1, ac = (t & 1) * 16;
    const int e0 = t * 8, e1 = (256 + t) * 8;
    const int r0 = e0 >> 5, c0 = e0 & 31;
    const int r1 = e1 >> 5, c1 = e1 & 31;

    f32x4 acc[4][4];
    f32x4 zf = {0.f, 0.f, 0.f, 0.f};
#pragma unroll
    for (int i = 0; i < 4; i++)
#pragma unroll
        for (int j = 0; j < 4; j++) acc[i][j] = zf;

    for (int k0 = 0; k0 < 1024; k0 += 32) {
        bf16x8 av0, av1;
        if (BF16A) {
            const bf16_t* ab = Ab + (size_t)(rowBase + ar) * 1024 + k0 + ac;
            av0 = *(const bf16x8*)(ab);
            av1 = *(const bf16x8*)(ab + 8);
        } else {
            const float4* ap = (const float4*)(A + (size_t)(rowBase + ar) * 1024 + k0 + ac);
            float4 af4[4];
#pragma unroll
            for (int i = 0; i < 4; i++) af4[i] = ap[i];
#pragma unroll
            for (int i = 0; i < 4; i++) {
                bf16x8& dstv = (i < 2) ? av0 : av1;
                int base = (i & 1) * 4;
                dstv[base + 0] = (bf16_t)af4[i].x; dstv[base + 1] = (bf16_t)af4[i].y;
                dstv[base + 2] = (bf16_t)af4[i].z; dstv[base + 3] = (bf16_t)af4[i].w;
            }
        }
        bf16x8 b0 = *(const bf16x8*)(Bt + (size_t)(colBase + r0) * 1024 + k0 + c0);
        bf16x8 b1 = *(const bf16x8*)(Bt + (size_t)(colBase + r1) * 1024 + k0 + c1);
        *(bf16x8*)(As + ar * GS + ac) = av0;
        *(bf16x8*)(As + ar * GS + ac + 8) = av1;
        *(bf16x8*)(Bs + r0 * GS + c0) = b0;
        *(bf16x8*)(Bs + r1 * GS + c1) = b1;
        __syncthreads();
        bf16x8 afr[4], bfr[4];
#pragma unroll
        for (int mi = 0; mi < 4; mi++)
            afr[mi] = *(const bf16x8*)(As + (wr * 64 + mi * 16 + lane15) * GS + quad * 8);
#pragma unroll
        for (int ni = 0; ni < 4; ni++)
            bfr[ni] = *(const bf16x8*)(Bs + (wc * 64 + ni * 16 + lane15) * GS + quad * 8);
#pragma unroll
        for (int mi = 0; mi < 4; mi++)
#pragma unroll
            for (int ni = 0; ni < 4; ni++)
                acc[mi][ni] = __builtin_amdgcn_mfma_f32_16x16x32_bf16(afr[mi], bfr[ni], acc[mi][ni], 0, 0, 0);
        __syncthreads();
    }

#pragma unroll
    for (int ni = 0; ni < 4; ni++) {
        int col = colBase + wc * 64 + ni * 16 + lane15;   // dout
        float bias = bia[col];
        int h = col >> 6, dk = col & 63;
#pragma unroll
        for (int mi = 0; mi < 4; mi++) {
#pragma unroll
            for (int r = 0; r < 4; r++) {
                int row = rowBase + wr * 64 + mi * 16 + quad * 4 + r;
                int b = row >> 11, l = row & 2047;
                float v = acc[mi][ni][r] + bias;
                size_t dst = (z < 2) ? ((((size_t)(b * 16 + h)) * 2048 + l) * 64 + dk)
                                     : ((((size_t)(b * 16 + h)) * 64 + dk) * 2048 + l);
                out[dst] = (bf16_t)v;
            }
        }
    }
}

// ---------------------------------------------------------------------------
// Output projection: A (concat) bf16, Bt (woT) bf16, out f32.
// 128x64 tile -> 512 blocks. m97 DMA staging, unpadded layout.
// ---------------------------------------------------------------------------
__global__ __launch_bounds__(256, 2) void gemm_out_kernel(
    const bf16_t* __restrict__ A, const bf16_t* __restrict__ Bt,
    const float* __restrict__ bia, float* __restrict__ out)
{
    __shared__ bf16_t As[128 * 32];     // 8 KB
    __shared__ bf16_t Bs[64 * 32];      // 4 KB
    const int t = threadIdx.x;
    const int w = t >> 6, lane = t & 63;
    const int lane15 = lane & 15, quad = lane >> 4;
    const int wr = w >> 1, wc = w & 1;
    const int rowBase = blockIdx.x * 128, colBase = blockIdx.y * 64;

    const int brow = lane >> 2, bcol = (lane & 3) * 8;  // bf16 chunk map

    f32x4 acc[4][2];
    f32x4 zf = {0.f, 0.f, 0.f, 0.f};
#pragma unroll
    for (int i = 0; i < 4; i++)
#pragma unroll
        for (int j = 0; j < 2; j++) acc[i][j] = zf;

    for (int k0 = 0; k0 < 1024; k0 += 32) {
#pragma unroll
        for (int j = 0; j < 2; j++) {   // 2 A-chunks per wave
            int chunk = w * 2 + j;
            load_lds16(A + (size_t)(rowBase + chunk * 16 + brow) * 1024 + k0 + bcol,
                       (char*)As + chunk * 1024);
        }
        {                               // 1 B-chunk per wave
            int chunk = w;
            load_lds16(Bt + (size_t)(colBase + chunk * 16 + brow) * 1024 + k0 + bcol,
                       (char*)Bs + chunk * 1024);
        }
        __syncthreads();
        bf16x8 afr[4], bfr[2];
#pragma unroll
        for (int mi = 0; mi < 4; mi++)
            afr[mi] = *(const bf16x8*)(As + (wr * 64 + mi * 16 + lane15) * 32 + quad * 8);
#pragma unroll
        for (int ni = 0; ni < 2; ni++)
            bfr[ni] = *(const bf16x8*)(Bs + (wc * 32 + ni * 16 + lane15) * 32 + quad * 8);
#pragma unroll
        for (int mi = 0; mi < 4; mi++)
#pragma unroll
            for (int ni = 0; ni < 2; ni++)
                acc[mi][ni] = __builtin_amdgcn_mfma_f32_16x16x32_bf16(afr[mi], bfr[ni], acc[mi][ni], 0, 0, 0);
        __syncthreads();
    }

#pragma unroll
    for (int ni = 0; ni < 2; ni++) {
        int col = colBase + wc * 32 + ni * 16 + lane15;
        float bias = bia[col];
#pragma unroll
        for (int mi = 0; mi < 4; mi++) {
#pragma unroll
            for (int r = 0; r < 4; r++) {
                int row = rowBase + wr * 64 + mi * 16 + quad * 4 + r;
                out[(size_t)row * 1024 + col] = acc[mi][ni][r] + bias;
            }
        }
    }
}

// ---------------------------------------------------------------------------
// Flash attention v10: SPLIT-K. v4's per-wave shape (32 q-rows/wave, 4 waves,
// 128-row q-tile) kept; rounds 6-8 proved time is invariant under the q/wave
// knob. NSPLIT=2 blocks each do 16 of 32 k-tiles (fixed-max exp2 => partials
// ADD: o=o0+o1, l=l0+l1) and atomicAdd f32 partials into pO [B,L,H,DK] /
// pL [B,L,H] (memset-zeroed; position-major so interhead reads coalesce like
// the old bf16 path). Grid (32,16,2)=1024 blocks = 4/CU (36 KB LDS).
// NSPLIT=1 = non-split fallback (stores attnout directly).
// Q,K bf16 [B,H,L,DK]; V bf16 [B,H,DK,L].
// ---------------------------------------------------------------------------
#define FS 72   // LDS row stride (bf16): 144 B = 16B-aligned, non-pow2 banks

template<int NSPLIT>
__global__ __launch_bounds__(256, 4) void flash_kernel(
    const bf16_t* __restrict__ QKV, const int* __restrict__ mask,
    const int* __restrict__ flags, bf16_t* __restrict__ attnout,
    float* __restrict__ pO, float* __restrict__ pL)
{
    __shared__ bf16_t Ks[64 * FS];          // 9 KB
    __shared__ bf16_t Vs[64 * FS];          // 9 KB
    __shared__ bf16_t Ps[8 * 16 * FS];      // 18 KB: 4 waves x 2 q-subtiles
    const int t = threadIdx.x, w = t >> 6, lane = t & 63;
    const int lane15 = lane & 15, quad = lane >> 4;
    const int qt = blockIdx.y, bh = blockIdx.x;   // qt in [0,16): 128-row tiles
    const int ks = blockIdx.z;
    const int kt0 = ks * (32 / NSPLIT), kt1 = kt0 + (32 / NSPLIT);
    const int b = bh >> 4, h = bh & 15;
    const bf16_t* Q  = QKV;
    const bf16_t* K  = QKV + 4194304;
    const bf16_t* Vt = QKV + 8388608;
    const int qrow0 = qt * 128 + w * 32;

    bf16x8 aq[2][2];
#pragma unroll
    for (int qf = 0; qf < 2; qf++) {
        const bf16_t* qb = Q + ((size_t)bh * 2048 + qrow0 + qf * 16 + lane15) * 64;
        aq[qf][0] = *(const bf16x8*)(qb + quad * 8);
        aq[qf][1] = *(const bf16x8*)(qb + 32 + quad * 8);
#pragma unroll
        for (int j = 0; j < 8; j++) {   // exact: *2^-3
            aq[qf][0][j] = (bf16_t)((float)aq[qf][0][j] * 0.125f);
            aq[qf][1][j] = (bf16_t)((float)aq[qf][1][j] * 0.125f);
        }
    }

    f32x4 zf = {0.f, 0.f, 0.f, 0.f};
    f32x4 o[2][4];
#pragma unroll
    for (int qf = 0; qf < 2; qf++)
#pragma unroll
        for (int df = 0; df < 4; df++) o[qf][df] = zf;
    f32x4 lsum[2] = {zf, zf};
    bf16_t* Pw0 = Ps + (w * 2 + 0) * 16 * FS;
    bf16_t* Pw1 = Ps + (w * 2 + 1) * 16 * FS;
    bf16x8 ones;
#pragma unroll
    for (int j = 0; j < 8; j++) ones[j] = (bf16_t)1.0f;

    const int e0 = t * 8, e1 = (256 + t) * 8;
    const int kr0 = e0 >> 6, kc0 = e0 & 63, kr1 = e1 >> 6, kc1 = e1 & 63;
    // 128-row q-tile spans flag tiles 2qt and 2qt+1 (64-row granularity)
    const int* fr0 = flags + (b * 32 + 2 * qt) * 32;
    const int* fr1 = fr0 + 32;
    const bf16_t* Kb  = K  + (size_t)bh * 131072;
    const bf16_t* Vtb = Vt + (size_t)bh * 131072;

    {
        int kn0 = kt0 * 64;
        bf16x8 k0v = *(const bf16x8*)(Kb  + (size_t)(kn0 + kr0) * 64 + kc0);
        bf16x8 k1v = *(const bf16x8*)(Kb  + (size_t)(kn0 + kr1) * 64 + kc1);
        bf16x8 v0v = *(const bf16x8*)(Vtb + (size_t)kr0 * 2048 + kn0 + kc0);
        bf16x8 v1v = *(const bf16x8*)(Vtb + (size_t)kr1 * 2048 + kn0 + kc1);
        *(bf16x8*)(Ks + kr0 * FS + kc0) = k0v;
        *(bf16x8*)(Ks + kr1 * FS + kc1) = k1v;
        *(bf16x8*)(Vs + kr0 * FS + kc0) = v0v;
        *(bf16x8*)(Vs + kr1 * FS + kc1) = v1v;
    }
    __syncthreads();

    for (int kt = kt0; kt < kt1; kt++) {
        bf16x8 k0v, k1v, v0v, v1v;
        if (kt + 1 < kt1) {             // prefetch next tile into registers
            int kn = (kt + 1) * 64;
            k0v = *(const bf16x8*)(Kb  + (size_t)(kn + kr0) * 64 + kc0);
            k1v = *(const bf16x8*)(Kb  + (size_t)(kn + kr1) * 64 + kc1);
            v0v = *(const bf16x8*)(Vtb + (size_t)kr0 * 2048 + kn + kc0);
            v1v = *(const bf16x8*)(Vtb + (size_t)kr1 * 2048 + kn + kc1);
        }

        f32x4 st[2][4];
#pragma unroll
        for (int kf = 0; kf < 4; kf++) {
            bf16x8 kb0 = *(const bf16x8*)(Ks + (kf * 16 + lane15) * FS + quad * 8);
            bf16x8 kb1 = *(const bf16x8*)(Ks + (kf * 16 + lane15) * FS + 32 + quad * 8);
#pragma unroll
            for (int qf = 0; qf < 2; qf++) {
                f32x4 a = zf;
                a = __builtin_amdgcn_mfma_f32_16x16x32_bf16(kb0, aq[qf][0], a, 0, 0, 0);
                a = __builtin_amdgcn_mfma_f32_16x16x32_bf16(kb1, aq[qf][1], a, 0, 0, 0);
                st[qf][kf] = a * 1.44269504f;
            }
        }
        if (!(fr0[kt] & fr1[kt])) {
#pragma unroll
            for (int qf = 0; qf < 2; qf++)
#pragma unroll
                for (int kf = 0; kf < 4; kf++)
#pragma unroll
                    for (int r = 0; r < 4; r++) {
                        int qrow = qrow0 + qf * 16 + lane15;
                        int kpos = kt * 64 + kf * 16 + quad * 4 + r;
                        if (mask[((size_t)b * 2048 + qrow) * 2048 + kpos] == 0)
                            st[qf][kf][r] = -1e30f;
                    }
        }
#pragma unroll
        for (int qf = 0; qf < 2; qf++) {
            bf16_t* Pq = qf ? Pw1 : Pw0;
#pragma unroll
            for (int kf = 0; kf < 4; kf++) {
                bf16x4 pv;
#pragma unroll
                for (int r = 0; r < 4; r++) pv[r] = (bf16_t)exp2f(st[qf][kf][r]);
                *(bf16x4*)(Pq + lane15 * FS + kf * 16 + quad * 4) = pv;
            }
        }
        bf16x8 pa[2][2];
        pa[0][0] = *(const bf16x8*)(Pw0 + lane15 * FS + quad * 8);
        pa[0][1] = *(const bf16x8*)(Pw0 + lane15 * FS + 32 + quad * 8);
        pa[1][0] = *(const bf16x8*)(Pw1 + lane15 * FS + quad * 8);
        pa[1][1] = *(const bf16x8*)(Pw1 + lane15 * FS + 32 + quad * 8);
#pragma unroll
        for (int qf = 0; qf < 2; qf++) {
            lsum[qf] = __builtin_amdgcn_mfma_f32_16x16x32_bf16(ones, pa[qf][0], lsum[qf], 0, 0, 0);
            lsum[qf] = __builtin_amdgcn_mfma_f32_16x16x32_bf16(ones, pa[qf][1], lsum[qf], 0, 0, 0);
        }
#pragma unroll
        for (int df = 0; df < 4; df++) {
            bf16x8 vb0 = *(const bf16x8*)(Vs + (df * 16 + lane15) * FS + quad * 8);
            bf16x8 vb1 = *(const bf16x8*)(Vs + (df * 16 + lane15) * FS + 32 + quad * 8);
#pragma unroll
            for (int qf = 0; qf < 2; qf++) {
                o[qf][df] = __builtin_amdgcn_mfma_f32_16x16x32_bf16(pa[qf][0], vb0, o[qf][df], 0, 0, 0);
                o[qf][df] = __builtin_amdgcn_mfma_f32_16x16x32_bf16(pa[qf][1], vb1, o[qf][df], 0, 0, 0);
            }
        }

        if (kt + 1 < kt1) {
            __syncthreads();            // all reads of Ks/Vs complete
            *(bf16x8*)(Ks + kr0 * FS + kc0) = k0v;
            *(bf16x8*)(Ks + kr1 * FS + kc1) = k1v;
            *(bf16x8*)(Vs + kr0 * FS + kc0) = v0v;
            *(bf16x8*)(Vs + kr1 * FS + kc1) = v1v;
            __syncthreads();            // writes visible to all waves
        }
    }

    if (NSPLIT == 1) {
#pragma unroll
        for (int qf = 0; qf < 2; qf++) {
            float lv = lsum[qf][0];
#pragma unroll
            for (int r = 0; r < 4; r++) {
                float inv = 1.0f / __shfl(lv, quad * 4 + r, 64);
                size_t row = (size_t)b * 2048 + qrow0 + qf * 16 + quad * 4 + r;
#pragma unroll
                for (int df = 0; df < 4; df++)
                    attnout[(row * 16 + h) * 64 + df * 16 + lane15] = (bf16_t)(o[qf][df][r] * inv);
            }
        }
    } else {
        // additive partials (fixed-max exp2): atomicAdd into zeroed pO/pL
        // pO layout [B,L,H,DK] (position-major); pL layout [B,L,H].
#pragma unroll
        for (int qf = 0; qf < 2; qf++) {
            if (lane < 16) {
                size_t l = (size_t)qrow0 + qf * 16 + lane;
                atomicAdd(&pL[((size_t)b * 2048 + l) * 16 + h], lsum[qf][0]);
            }
#pragma unroll
            for (int df = 0; df < 4; df++)
#pragma unroll
                for (int r = 0; r < 4; r++) {
                    size_t l = (size_t)qrow0 + qf * 16 + quad * 4 + r;
                    atomicAdd(&pO[(((size_t)b * 2048 + l) * 16 + h) * 64 + df * 16 + lane15],
                              o[qf][df][r]);
                }
        }
    }
}

// ---------------------------------------------------------------------------
// Inter-head attention: one wave per position (b,l).
// F32IN=true: reads f32 partials pO [B,L,H,DK] / pL [B,L,H] (split-K flash)
// and normalizes inline. F32IN=false: reads bf16 attn [B,L,H,DK].
// ---------------------------------------------------------------------------
template<bool F32IN>
__global__ __launch_bounds__(256, 2) void interhead_kernel(
    const bf16_t* __restrict__ attn,
    const float* __restrict__ pO, const float* __restrict__ pL,
    const bf16_t* __restrict__ whqT, const float* __restrict__ bhq,
    const bf16_t* __restrict__ whkT, const float* __restrict__ bhk,
    const bf16_t* __restrict__ whvT, const float* __restrict__ bhv,
    bf16_t* __restrict__ concat)
{
    __shared__ bf16_t lds[4 * 4608];
    const int t = threadIdx.x, w = t >> 6, lane = t & 63;
    const int lane15 = lane & 15, quad = lane >> 4;
    bf16_t* Qh  = lds + w * 4608;   // [16][64]
    bf16_t* Kh  = Qh + 1024;        // [16][64]
    bf16_t* VhT = Kh + 1024;        // [64][32] (k-padded)
    bf16_t* P16 = VhT + 2048;       // [16][32] (k-padded)
    const int p = blockIdx.x * 4 + w;

    bf16x8 z8 = {(bf16_t)0.f, (bf16_t)0.f, (bf16_t)0.f, (bf16_t)0.f,
                 (bf16_t)0.f, (bf16_t)0.f, (bf16_t)0.f, (bf16_t)0.f};
    ((bf16x8*)P16)[lane] = z8;
#pragma unroll
    for (int i = 0; i < 4; i++) ((bf16x8*)VhT)[i * 64 + lane] = z8;

    bf16x8 ha0, ha1;
    if (F32IN) {
        size_t r16 = (size_t)p * 16 + lane15;    // (b*2048+l)*16 + h
        float inv = 1.0f / pL[r16];
        const float* src = pO + r16 * 64;
        f32x4 u0 = *(const f32x4*)(src + quad * 8);
        f32x4 u1 = *(const f32x4*)(src + quad * 8 + 4);
        f32x4 u2 = *(const f32x4*)(src + 32 + quad * 8);
        f32x4 u3 = *(const f32x4*)(src + 32 + quad * 8 + 4);
#pragma unroll
        for (int j = 0; j < 4; j++) {
            ha0[j]     = (bf16_t)(u0[j] * inv);
            ha0[j + 4] = (bf16_t)(u1[j] * inv);
            ha1[j]     = (bf16_t)(u2[j] * inv);
            ha1[j + 4] = (bf16_t)(u3[j] * inv);
        }
    } else {
        const bf16_t* hb = attn + ((size_t)p * 16 + lane15) * 64;
        ha0 = *(const bf16x8*)(hb + quad * 8);
        ha1 = *(const bf16x8*)(hb + 32 + quad * 8);
    }

    const bf16_t* Wt[3] = {whqT, whkT, whvT};
    const float*  Bb[3] = {bhq, bhk, bhv};
    f32x4 zf = {0.f, 0.f, 0.f, 0.f};
#pragma unroll
    for (int m3 = 0; m3 < 3; m3++) {
#pragma unroll
        for (int nf = 0; nf < 4; nf++) {
            f32x4 acc = zf;
            bf16x8 wb0 = *(const bf16x8*)(Wt[m3] + (nf * 16 + lane15) * 64 + quad * 8);
            bf16x8 wb1 = *(const bf16x8*)(Wt[m3] + (nf * 16 + lane15) * 64 + 32 + quad * 8);
            acc = __builtin_amdgcn_mfma_f32_16x16x32_bf16(ha0, wb0, acc, 0, 0, 0);
            acc = __builtin_amdgcn_mfma_f32_16x16x32_bf16(ha1, wb1, acc, 0, 0, 0);
            float bias = Bb[m3][nf * 16 + lane15];
#pragma unroll
            for (int r = 0; r < 4; r++) {
                float v = acc[r] + bias;
                if (m3 == 0) v *= 0.125f;   // fold inter scale into Qh (exact)
                if (m3 == 2) VhT[(nf * 16 + lane15) * 32 + quad * 4 + r] = (bf16_t)v;
                else if (m3 == 0) Qh[(quad * 4 + r) * 64 + nf * 16 + lane15] = (bf16_t)v;
                else Kh[(quad * 4 + r) * 64 + nf * 16 + lane15] = (bf16_t)v;
            }
        }
    }
    __syncthreads();

    bf16x8 qa0 = *(const bf16x8*)(Qh + lane15 * 64 + quad * 8);
    bf16x8 qa1 = *(const bf16x8*)(Qh + lane15 * 64 + 32 + quad * 8);
    bf16x8 kb0 = *(const bf16x8*)(Kh + lane15 * 64 + quad * 8);
    bf16x8 kb1 = *(const bf16x8*)(Kh + lane15 * 64 + 32 + quad * 8);
    f32x4 s = zf;
    s = __builtin_amdgcn_mfma_f32_16x16x32_bf16(qa0, kb0, s, 0, 0, 0);
    s = __builtin_amdgcn_mfma_f32_16x16x32_bf16(qa1, kb1, s, 0, 0, 0);
#pragma unroll
    for (int r = 0; r < 4; r++) {
        float v = s[r];
        float mx = v;
        mx = fmaxf(mx, __shfl_xor(mx, 1));
        mx = fmaxf(mx, __shfl_xor(mx, 2));
        mx = fmaxf(mx, __shfl_xor(mx, 4));
        mx = fmaxf(mx, __shfl_xor(mx, 8));
        float pv = __expf(v - mx);
        float sm = pv;
        sm += __shfl_xor(sm, 1);
        sm += __shfl_xor(sm, 2);
        sm += __shfl_xor(sm, 4);
        sm += __shfl_xor(sm, 8);
        P16[(quad * 4 + r) * 32 + lane15] = (bf16_t)(pv / sm);
    }
    __syncthreads();

    bf16x8 pa = *(const bf16x8*)(P16 + lane15 * 32 + quad * 8);
    bf16_t* outp = concat + (size_t)p * 1024;
#pragma unroll
    for (int df = 0; df < 4; df++) {
        bf16x8 vb = *(const bf16x8*)(VhT + (df * 16 + lane15) * 32 + quad * 8);
        f32x4 mix = zf;
        mix = __builtin_amdgcn_mfma_f32_16x16x32_bf16(pa, vb, mix, 0, 0, 0);
#pragma unroll
        for (int r = 0; r < 4; r++)
            outp[(quad * 4 + r) * 64 + df * 16 + lane15] = (bf16_t)mix[r];
    }
}

// ---------------------------------------------------------------------------
extern "C" void kernel_launch(void* const* d_in, const int* in_sizes, int n_in,
                              void* d_out, int out_size, void* d_ws, size_t ws_size,
                              hipStream_t stream)
{
    const float* q_in = (const float*)d_in[0];
    const float* k_in = (const float*)d_in[1];
    const float* v_in = (const float*)d_in[2];
    const int*   mask = (const int*)d_in[3];
    const float* wq = (const float*)d_in[4];
    const float* bq = (const float*)d_in[5];
    const float* wk = (const float*)d_in[6];
    const float* bk = (const float*)d_in[7];
    const float* wv = (const float*)d_in[8];
    const float* bv = (const float*)d_in[9];
    const float* wo = (const float*)d_in[10];
    const float* bo = (const float*)d_in[11];
    const float* whq = (const float*)d_in[12];
    const float* bhq = (const float*)d_in[13];
    const float* whk = (const float*)d_in[14];
    const float* bhk = (const float*)d_in[15];
    const float* whv = (const float*)d_in[16];
    const float* bhv = (const float*)d_in[17];
    float* out = (float*)d_out;         // [4096][1024] f32 = 16 MB

    char* ws = (char*)d_ws;
    bf16_t* qkvb  = (bf16_t*)ws;                       // 24 MB: Q|K|Vt
    bf16_t* concat = qkvb;                             // Q region, post-flash
    bf16_t* woT   = (bf16_t*)(ws + 8u * 1024 * 1024);  // K region, post-flash
    bf16_t* whqT  = (bf16_t*)(ws + 10u * 1024 * 1024);
    bf16_t* whkT  = whqT + 4096;
    bf16_t* whvT  = whqT + 8192;
    bf16_t* abf   = (bf16_t*)(ws + 24u * 1024 * 1024); // 24 MB bf16 A (bigws)
    float*  pO    = (float*)(ws + 24u * 1024 * 1024);  // 16 MB f32 (overlays abf, post-qkv)
    float*  pL    = pO + (size_t)4096 * 16 * 64;       // 256 KB f32
    bf16_t* attnb = (bf16_t*)d_out;                    // 8 MB bf16 in d_out (fallback)
    bf16_t* wqkvT = (bf16_t*)((char*)d_out + 8u * 1024 * 1024);
    int*    flags = (int*)((char*)d_out + 14u * 1024 * 1024);

    const bool bigws = (ws_size >= 48u * 1024 * 1024);

    prep1_kernel<<<bigws ? 4352 : 2816, 256, 0, stream>>>(
        mask, flags, wq, wk, wv, wqkvT, q_in, k_in, v_in, abf);
    if (bigws)
        gemm_qkv_t<true><<<dim3(32, 8, 3), 256, 0, stream>>>(
            q_in, k_in, v_in, abf, wqkvT, bq, bk, bv, qkvb);
    else
        gemm_qkv_t<false><<<dim3(32, 8, 3), 256, 0, stream>>>(
            q_in, k_in, v_in, abf, wqkvT, bq, bk, bv, qkvb);
    if (bigws) {
        // zero partials (stream-ordered after gemm_qkv's last abf read)
        hipMemsetAsync(pO, 0, (size_t)4096 * 16 * 64 * 4 + (size_t)4096 * 16 * 4, stream);
        flash_kernel<2><<<dim3(32, 16, 2), 256, 0, stream>>>(
            qkvb, mask, flags, attnb, pO, pL);
    } else {
        flash_kernel<1><<<dim3(32, 16, 1), 256, 0, stream>>>(
            qkvb, mask, flags, attnb, pO, pL);
    }
    prep2_kernel<<<259, 256, 0, stream>>>(wo, woT, whq, whk, whv, whqT, whkT, whvT);
    if (bigws)
        interhead_kernel<true><<<1024, 256, 0, stream>>>(
            attnb, pO, pL, whqT, bhq, whkT, bhk, whvT, bhv, concat);
    else
        interhead_kernel<false><<<1024, 256, 0, stream>>>(
            attnb, pO, pL, whqT, bhq, whkT, bhk, whvT, bhv, concat);
    gemm_out_kernel<<<dim3(32, 16), 256, 0, stream>>>(concat, woT, bo, out);
    (void)in_sizes; (void)n_in; (void)out_size; (void)ws_size;
}

// Round 11
// 306.156 us; speedup vs baseline: 1.0651x; 1.0651x over previous
//
#include <hip/hip_runtime.h>
#include <hip/hip_bf16.h>

typedef __bf16 bf16_t;
typedef __bf16 bf16x4 __attribute__((ext_vector_type(4)));
typedef __bf16 bf16x8 __attribute__((ext_vector_type(8)));
typedef float f32x4 __attribute__((ext_vector_type(4)));

typedef __attribute__((address_space(1))) unsigned char glob_u8;
typedef __attribute__((address_space(3))) unsigned char lds_u8;

__device__ __forceinline__ void load_lds16(const void* g, void* l) {
    __builtin_amdgcn_global_load_lds((glob_u8*)g, (lds_u8*)l, 16, 0, 0);
}

// ---------------------------------------------------------------------------
// prep1: maskflags (blocks 0..2047) + qkv weight transposes (2048..2815)
//        + OPTIONAL A f32->bf16 pre-convert (blocks 2816..4351, 512/z)
// NOTE: woT / inter-head transposes are NOT here -- they live in the K region
// of qkvb and may only be written after flash consumed K (prep2, below).
// ---------------------------------------------------------------------------
__global__ void prep1_kernel(const int* __restrict__ mask, int* __restrict__ flags,
                             const float* __restrict__ wq, const float* __restrict__ wk,
                             const float* __restrict__ wv, bf16_t* __restrict__ wqkvT,
                             const float* __restrict__ aq, const float* __restrict__ ak,
                             const float* __restrict__ av, bf16_t* __restrict__ abf)
{
    const int bid = blockIdx.x, t = threadIdx.x;
    if (bid < 2048) {
        int b = bid >> 10, qt = (bid >> 5) & 31, kt = bid & 31;
        int ok = 1;
#pragma unroll
        for (int i = 0; i < 16; i++) {
            int e = t + i * 256; int r = e >> 6, c = e & 63;
            ok &= (mask[((size_t)b * 2048 + qt * 64 + r) * 2048 + kt * 64 + c] != 0) ? 1 : 0;
        }
        ok = __syncthreads_and(ok);
        if (t == 0) flags[bid] = ok;
    } else if (bid < 2816) {
        __shared__ bf16_t tile[64][65];
        int idx = bid - 2048;
        int z = idx >> 8, rem = idx & 255;
        const float* src = (z == 0) ? wq : (z == 1) ? wk : wv;
        bf16_t* dst = wqkvT + (size_t)z * 1048576;
        int rB = (rem >> 4) * 64, cB = (rem & 15) * 64;
#pragma unroll
        for (int i = 0; i < 16; i++) {
            int e = t + i * 256; int r = e >> 6, c = e & 63;
            tile[r][c] = (bf16_t)src[(size_t)(rB + r) * 1024 + cB + c];
        }
        __syncthreads();
#pragma unroll
        for (int i = 0; i < 16; i++) {
            int e = t + i * 256; int r = e >> 6, c = e & 63;
            dst[(size_t)(cB + r) * 1024 + rB + c] = tile[c][r];
        }
    } else {
        // A pre-convert: 1536 blocks, each 256 thr x 32 elems = 8192 elems.
        int idx = bid - 2816;                 // 0..1535
        int z = idx >> 9, seg = idx & 511;    // 512 blocks per z
        const float* src = (z == 0) ? aq : (z == 1) ? ak : av;
        bf16_t* dst = abf + (size_t)z * 4194304;
        size_t base = (size_t)seg * 8192 + (size_t)t * 32;
#pragma unroll
        for (int j = 0; j < 4; j++) {         // 4 x (8 f32 -> bf16x8)
            f32x4 u = *(const f32x4*)(src + base + j * 8);
            f32x4 v = *(const f32x4*)(src + base + j * 8 + 4);
            bf16x8 o;
            o[0] = (bf16_t)u[0]; o[1] = (bf16_t)u[1];
            o[2] = (bf16_t)u[2]; o[3] = (bf16_t)u[3];
            o[4] = (bf16_t)v[0]; o[5] = (bf16_t)v[1];
            o[6] = (bf16_t)v[2]; o[7] = (bf16_t)v[3];
            *(bf16x8*)(dst + base + j * 8) = o;
        }
    }
}

// ---------------------------------------------------------------------------
// prep2: wo transpose (blocks 0..255) + small inter-head weight transposes.
// MUST run after flash_kernel: woT/whqT live in the (then-dead) K region.
// ---------------------------------------------------------------------------
__global__ void prep2_kernel(const float* __restrict__ wo, bf16_t* __restrict__ woT,
                             const float* __restrict__ s0, const float* __restrict__ s1,
                             const float* __restrict__ s2,
                             bf16_t* __restrict__ d0, bf16_t* __restrict__ d1, bf16_t* __restrict__ d2)
{
    const int bid = blockIdx.x, t = threadIdx.x;
    if (bid < 256) {
        __shared__ bf16_t tile[64][65];
        int rB = (bid >> 4) * 64, cB = (bid & 15) * 64;
#pragma unroll
        for (int i = 0; i < 16; i++) {
            int e = t + i * 256; int r = e >> 6, c = e & 63;
            tile[r][c] = (bf16_t)wo[(size_t)(rB + r) * 1024 + cB + c];
        }
        __syncthreads();
#pragma unroll
        for (int i = 0; i < 16; i++) {
            int e = t + i * 256; int r = e >> 6, c = e & 63;
            woT[(size_t)(cB + r) * 1024 + rB + c] = tile[c][r];
        }
    } else {
        int z = bid - 256;
        const float* src = (z == 0) ? s0 : (z == 1) ? s1 : s2;
        bf16_t* dst = (z == 0) ? d0 : (z == 1) ? d1 : d2;
#pragma unroll
        for (int i = 0; i < 16; i++) {
            int e = t + i * 256; int r = e >> 6, c = e & 63;
            dst[c * 64 + r] = (bf16_t)src[r * 64 + c];
        }
    }
}

// ---------------------------------------------------------------------------
// QKV GEMM v7: round-0 v1 structure (128x128 tile, register staging, GS=40,
// single-buffered, grid (32,8,3)). BF16A=true stages A from the pre-converted
// bf16 copy; false is the exact f32 fallback. Same LDS image bit-for-bit.
// ---------------------------------------------------------------------------
#define GS 40   // GEMM LDS row stride (bf16 elems) for a 32-wide K tile

template<bool BF16A>
__global__ __launch_bounds__(256, 2) void gemm_qkv_t(
    const float* __restrict__ Aq, const float* __restrict__ Ak, const float* __restrict__ Av,
    const bf16_t* __restrict__ Abf,
    const bf16_t* __restrict__ WT,
    const float* __restrict__ bq, const float* __restrict__ bk, const float* __restrict__ bv,
    bf16_t* __restrict__ outbase)
{
    __shared__ bf16_t As[128 * GS];
    __shared__ bf16_t Bs[128 * GS];
    const int z = blockIdx.z;
    const float* A    = (z == 0) ? Aq : (z == 1) ? Ak : Av;
    const bf16_t* Ab  = Abf + (size_t)z * 4194304;
    const bf16_t* Bt  = WT + (size_t)z * 1048576;
    const float* bia  = (z == 0) ? bq : (z == 1) ? bk : bv;
    bf16_t* out = outbase + (size_t)z * 4194304;

    const int t = threadIdx.x;
    const int w = t >> 6, lane = t & 63;
    const int lane15 = lane & 15, quad = lane >> 4;
    const int wr = w >> 1, wc = w & 1;
    const int rowBase = blockIdx.x * 128, colBase = blockIdx.y * 128;

    const int ar = t >> 1, ac = (t & 1) * 16;
    const int e0 = t * 8, e1 = (256 + t) * 8;
    const int r0 = e0 >> 5, c0 = e0 & 31;
    const int r1 = e1 >> 5, c1 = e1 & 31;

    f32x4 acc[4][4];
    f32x4 zf = {0.f, 0.f, 0.f, 0.f};
#pragma unroll
    for (int i = 0; i < 4; i++)
#pragma unroll
        for (int j = 0; j < 4; j++) acc[i][j] = zf;

    for (int k0 = 0; k0 < 1024; k0 += 32) {
        bf16x8 av0, av1;
        if (BF16A) {
            const bf16_t* ab = Ab + (size_t)(rowBase + ar) * 1024 + k0 + ac;
            av0 = *(const bf16x8*)(ab);
            av1 = *(const bf16x8*)(ab + 8);
        } else {
            const float4* ap = (const float4*)(A + (size_t)(rowBase + ar) * 1024 + k0 + ac);
            float4 af4[4];
#pragma unroll
            for (int i = 0; i < 4; i++) af4[i] = ap[i];
#pragma unroll
            for (int i = 0; i < 4; i++) {
                bf16x8& dstv = (i < 2) ? av0 : av1;
                int base = (i & 1) * 4;
                dstv[base + 0] = (bf16_t)af4[i].x; dstv[base + 1] = (bf16_t)af4[i].y;
                dstv[base + 2] = (bf16_t)af4[i].z; dstv[base + 3] = (bf16_t)af4[i].w;
            }
        }
        bf16x8 b0 = *(const bf16x8*)(Bt + (size_t)(colBase + r0) * 1024 + k0 + c0);
        bf16x8 b1 = *(const bf16x8*)(Bt + (size_t)(colBase + r1) * 1024 + k0 + c1);
        *(bf16x8*)(As + ar * GS + ac) = av0;
        *(bf16x8*)(As + ar * GS + ac + 8) = av1;
        *(bf16x8*)(Bs + r0 * GS + c0) = b0;
        *(bf16x8*)(Bs + r1 * GS + c1) = b1;
        __syncthreads();
        bf16x8 afr[4], bfr[4];
#pragma unroll
        for (int mi = 0; mi < 4; mi++)
            afr[mi] = *(const bf16x8*)(As + (wr * 64 + mi * 16 + lane15) * GS + quad * 8);
#pragma unroll
        for (int ni = 0; ni < 4; ni++)
            bfr[ni] = *(const bf16x8*)(Bs + (wc * 64 + ni * 16 + lane15) * GS + quad * 8);
#pragma unroll
        for (int mi = 0; mi < 4; mi++)
#pragma unroll
            for (int ni = 0; ni < 4; ni++)
                acc[mi][ni] = __builtin_amdgcn_mfma_f32_16x16x32_bf16(afr[mi], bfr[ni], acc[mi][ni], 0, 0, 0);
        __syncthreads();
    }

#pragma unroll
    for (int ni = 0; ni < 4; ni++) {
        int col = colBase + wc * 64 + ni * 16 + lane15;   // dout
        float bias = bia[col];
        int h = col >> 6, dk = col & 63;
#pragma unroll
        for (int mi = 0; mi < 4; mi++) {
#pragma unroll
            for (int r = 0; r < 4; r++) {
                int row = rowBase + wr * 64 + mi * 16 + quad * 4 + r;
                int b = row >> 11, l = row & 2047;
                float v = acc[mi][ni][r] + bias;
                size_t dst = (z < 2) ? ((((size_t)(b * 16 + h)) * 2048 + l) * 64 + dk)
                                     : ((((size_t)(b * 16 + h)) * 64 + dk) * 2048 + l);
                out[dst] = (bf16_t)v;
            }
        }
    }
}

// ---------------------------------------------------------------------------
// Output projection: A (concat) bf16, Bt (woT) bf16, out f32.
// 128x64 tile -> 512 blocks. m97 DMA staging, unpadded layout.
// ---------------------------------------------------------------------------
__global__ __launch_bounds__(256, 2) void gemm_out_kernel(
    const bf16_t* __restrict__ A, const bf16_t* __restrict__ Bt,
    const float* __restrict__ bia, float* __restrict__ out)
{
    __shared__ bf16_t As[128 * 32];     // 8 KB
    __shared__ bf16_t Bs[64 * 32];      // 4 KB
    const int t = threadIdx.x;
    const int w = t >> 6, lane = t & 63;
    const int lane15 = lane & 15, quad = lane >> 4;
    const int wr = w >> 1, wc = w & 1;
    const int rowBase = blockIdx.x * 128, colBase = blockIdx.y * 64;

    const int brow = lane >> 2, bcol = (lane & 3) * 8;  // bf16 chunk map

    f32x4 acc[4][2];
    f32x4 zf = {0.f, 0.f, 0.f, 0.f};
#pragma unroll
    for (int i = 0; i < 4; i++)
#pragma unroll
        for (int j = 0; j < 2; j++) acc[i][j] = zf;

    for (int k0 = 0; k0 < 1024; k0 += 32) {
#pragma unroll
        for (int j = 0; j < 2; j++) {   // 2 A-chunks per wave
            int chunk = w * 2 + j;
            load_lds16(A + (size_t)(rowBase + chunk * 16 + brow) * 1024 + k0 + bcol,
                       (char*)As + chunk * 1024);
        }
        {                               // 1 B-chunk per wave
            int chunk = w;
            load_lds16(Bt + (size_t)(colBase + chunk * 16 + brow) * 1024 + k0 + bcol,
                       (char*)Bs + chunk * 1024);
        }
        __syncthreads();
        bf16x8 afr[4], bfr[2];
#pragma unroll
        for (int mi = 0; mi < 4; mi++)
            afr[mi] = *(const bf16x8*)(As + (wr * 64 + mi * 16 + lane15) * 32 + quad * 8);
#pragma unroll
        for (int ni = 0; ni < 2; ni++)
            bfr[ni] = *(const bf16x8*)(Bs + (wc * 32 + ni * 16 + lane15) * 32 + quad * 8);
#pragma unroll
        for (int mi = 0; mi < 4; mi++)
#pragma unroll
            for (int ni = 0; ni < 2; ni++)
                acc[mi][ni] = __builtin_amdgcn_mfma_f32_16x16x32_bf16(afr[mi], bfr[ni], acc[mi][ni], 0, 0, 0);
        __syncthreads();
    }

#pragma unroll
    for (int ni = 0; ni < 2; ni++) {
        int col = colBase + wc * 32 + ni * 16 + lane15;
        float bias = bia[col];
#pragma unroll
        for (int mi = 0; mi < 4; mi++) {
#pragma unroll
            for (int r = 0; r < 4; r++) {
                int row = rowBase + wr * 64 + mi * 16 + quad * 4 + r;
                out[(size_t)row * 1024 + col] = acc[mi][ni][r] + bias;
            }
        }
    }
}

// ---------------------------------------------------------------------------
// Flash attention v11: round-6 v4 VERBATIM (best measured: 74.5 us --
// double-buffered K/V, 128-row q-tiles, 1 barrier/kt, grid (32,16)) + T5
// s_setprio around the MFMA clusters. Rounds 6-10 proved time is invariant
// under occupancy/LDS-volume/split-K => per-wave dependency-chain floor;
// setprio is the one cheap lever matching the mechanism (2 independent
// blocks/CU at different phases -- the m191-positive attn regime).
// Q,K bf16 [B,H,L,DK]; V bf16 [B,H,DK,L]. attn out [B,L,H,DK].
// ---------------------------------------------------------------------------
#define FS 72   // LDS row stride (bf16): 144 B = 16B-aligned, non-pow2 banks

__global__ __launch_bounds__(256, 2) void flash_kernel(
    const bf16_t* __restrict__ QKV, const int* __restrict__ mask,
    const int* __restrict__ flags, bf16_t* __restrict__ attnout)
{
    __shared__ bf16_t Ks[2][64 * FS];
    __shared__ bf16_t Vs[2][64 * FS];
    __shared__ bf16_t Ps[8 * 16 * FS];      // 4 waves x 2 q-subtiles
    const int t = threadIdx.x, w = t >> 6, lane = t & 63;
    const int lane15 = lane & 15, quad = lane >> 4;
    const int qt = blockIdx.y, bh = blockIdx.x;   // swizzled
    const int b = bh >> 4, h = bh & 15;
    const bf16_t* Q  = QKV;
    const bf16_t* K  = QKV + 4194304;
    const bf16_t* Vt = QKV + 8388608;
    const int qrow0 = qt * 128 + w * 32;

    bf16x8 aq[2][2];
#pragma unroll
    for (int qf = 0; qf < 2; qf++) {
        const bf16_t* qb = Q + ((size_t)bh * 2048 + qrow0 + qf * 16 + lane15) * 64;
        aq[qf][0] = *(const bf16x8*)(qb + quad * 8);
        aq[qf][1] = *(const bf16x8*)(qb + 32 + quad * 8);
#pragma unroll
        for (int j = 0; j < 8; j++) {   // exact: *2^-3
            aq[qf][0][j] = (bf16_t)((float)aq[qf][0][j] * 0.125f);
            aq[qf][1][j] = (bf16_t)((float)aq[qf][1][j] * 0.125f);
        }
    }

    f32x4 zf = {0.f, 0.f, 0.f, 0.f};
    f32x4 o[2][4];
#pragma unroll
    for (int qf = 0; qf < 2; qf++)
#pragma unroll
        for (int df = 0; df < 4; df++) o[qf][df] = zf;
    f32x4 lsum[2] = {zf, zf};
    bf16_t* Pw0 = Ps + (w * 2 + 0) * 16 * FS;
    bf16_t* Pw1 = Ps + (w * 2 + 1) * 16 * FS;
    bf16x8 ones;
#pragma unroll
    for (int j = 0; j < 8; j++) ones[j] = (bf16_t)1.0f;

    const int e0 = t * 8, e1 = (256 + t) * 8;
    const int kr0 = e0 >> 6, kc0 = e0 & 63, kr1 = e1 >> 6, kc1 = e1 & 63;
    const int* flagrow = flags + (b * 32 + qt) * 32;
    const bf16_t* Kb  = K  + (size_t)bh * 131072;
    const bf16_t* Vtb = Vt + (size_t)bh * 131072;

    {
        bf16x8 k0v = *(const bf16x8*)(Kb  + (size_t)kr0 * 64 + kc0);
        bf16x8 k1v = *(const bf16x8*)(Kb  + (size_t)kr1 * 64 + kc1);
        bf16x8 v0v = *(const bf16x8*)(Vtb + (size_t)kr0 * 2048 + kc0);
        bf16x8 v1v = *(const bf16x8*)(Vtb + (size_t)kr1 * 2048 + kc1);
        *(bf16x8*)(Ks[0] + kr0 * FS + kc0) = k0v;
        *(bf16x8*)(Ks[0] + kr1 * FS + kc1) = k1v;
        *(bf16x8*)(Vs[0] + kr0 * FS + kc0) = v0v;
        *(bf16x8*)(Vs[0] + kr1 * FS + kc1) = v1v;
    }
    __syncthreads();

    for (int kt = 0; kt < 32; kt++) {
        const int cur = kt & 1, nxt = cur ^ 1;
        bf16x8 k0v, k1v, v0v, v1v;
        if (kt + 1 < 32) {
            int kn = (kt + 1) * 64;
            k0v = *(const bf16x8*)(Kb  + (size_t)(kn + kr0) * 64 + kc0);
            k1v = *(const bf16x8*)(Kb  + (size_t)(kn + kr1) * 64 + kc1);
            v0v = *(const bf16x8*)(Vtb + (size_t)kr0 * 2048 + kn + kc0);
            v1v = *(const bf16x8*)(Vtb + (size_t)kr1 * 2048 + kn + kc1);
        }

        f32x4 st[2][4];
        __builtin_amdgcn_s_setprio(1);
#pragma unroll
        for (int kf = 0; kf < 4; kf++) {
            bf16x8 kb0 = *(const bf16x8*)(Ks[cur] + (kf * 16 + lane15) * FS + quad * 8);
            bf16x8 kb1 = *(const bf16x8*)(Ks[cur] + (kf * 16 + lane15) * FS + 32 + quad * 8);
#pragma unroll
            for (int qf = 0; qf < 2; qf++) {
                f32x4 a = zf;
                a = __builtin_amdgcn_mfma_f32_16x16x32_bf16(kb0, aq[qf][0], a, 0, 0, 0);
                a = __builtin_amdgcn_mfma_f32_16x16x32_bf16(kb1, aq[qf][1], a, 0, 0, 0);
                st[qf][kf] = a * 1.44269504f;
            }
        }
        __builtin_amdgcn_s_setprio(0);
        if (kt + 1 < 32) {
            *(bf16x8*)(Ks[nxt] + kr0 * FS + kc0) = k0v;
            *(bf16x8*)(Ks[nxt] + kr1 * FS + kc1) = k1v;
            *(bf16x8*)(Vs[nxt] + kr0 * FS + kc0) = v0v;
            *(bf16x8*)(Vs[nxt] + kr1 * FS + kc1) = v1v;
        }
        if (!flagrow[kt]) {
#pragma unroll
            for (int qf = 0; qf < 2; qf++)
#pragma unroll
                for (int kf = 0; kf < 4; kf++)
#pragma unroll
                    for (int r = 0; r < 4; r++) {
                        int qrow = qrow0 + qf * 16 + lane15;
                        int kpos = kt * 64 + kf * 16 + quad * 4 + r;
                        if (mask[((size_t)b * 2048 + qrow) * 2048 + kpos] == 0)
                            st[qf][kf][r] = -1e30f;
                    }
        }
#pragma unroll
        for (int qf = 0; qf < 2; qf++) {
            bf16_t* Pq = qf ? Pw1 : Pw0;
#pragma unroll
            for (int kf = 0; kf < 4; kf++) {
                bf16x4 pv;
#pragma unroll
                for (int r = 0; r < 4; r++) pv[r] = (bf16_t)exp2f(st[qf][kf][r]);
                *(bf16x4*)(Pq + lane15 * FS + kf * 16 + quad * 4) = pv;
            }
        }
        bf16x8 pa[2][2];
        pa[0][0] = *(const bf16x8*)(Pw0 + lane15 * FS + quad * 8);
        pa[0][1] = *(const bf16x8*)(Pw0 + lane15 * FS + 32 + quad * 8);
        pa[1][0] = *(const bf16x8*)(Pw1 + lane15 * FS + quad * 8);
        pa[1][1] = *(const bf16x8*)(Pw1 + lane15 * FS + 32 + quad * 8);
        __builtin_amdgcn_s_setprio(1);
#pragma unroll
        for (int qf = 0; qf < 2; qf++) {
            lsum[qf] = __builtin_amdgcn_mfma_f32_16x16x32_bf16(ones, pa[qf][0], lsum[qf], 0, 0, 0);
            lsum[qf] = __builtin_amdgcn_mfma_f32_16x16x32_bf16(ones, pa[qf][1], lsum[qf], 0, 0, 0);
        }
#pragma unroll
        for (int df = 0; df < 4; df++) {
            bf16x8 vb0 = *(const bf16x8*)(Vs[cur] + (df * 16 + lane15) * FS + quad * 8);
            bf16x8 vb1 = *(const bf16x8*)(Vs[cur] + (df * 16 + lane15) * FS + 32 + quad * 8);
#pragma unroll
            for (int qf = 0; qf < 2; qf++) {
                o[qf][df] = __builtin_amdgcn_mfma_f32_16x16x32_bf16(pa[qf][0], vb0, o[qf][df], 0, 0, 0);
                o[qf][df] = __builtin_amdgcn_mfma_f32_16x16x32_bf16(pa[qf][1], vb1, o[qf][df], 0, 0, 0);
            }
        }
        __builtin_amdgcn_s_setprio(0);
        __syncthreads();
    }

#pragma unroll
    for (int qf = 0; qf < 2; qf++) {
        float lv = lsum[qf][0];
#pragma unroll
        for (int r = 0; r < 4; r++) {
            float inv = 1.0f / __shfl(lv, quad * 4 + r, 64);
            size_t row = (size_t)b * 2048 + qrow0 + qf * 16 + quad * 4 + r;
#pragma unroll
            for (int df = 0; df < 4; df++)
                attnout[(row * 16 + h) * 64 + df * 16 + lane15] = (bf16_t)(o[qf][df][r] * inv);
        }
    }
}

// ---------------------------------------------------------------------------
// Inter-head attention: one wave per position (b,l). attn is [B,L,H,DK].
// ---------------------------------------------------------------------------
__global__ __launch_bounds__(256, 2) void interhead_kernel(
    const bf16_t* __restrict__ attn,
    const bf16_t* __restrict__ whqT, const float* __restrict__ bhq,
    const bf16_t* __restrict__ whkT, const float* __restrict__ bhk,
    const bf16_t* __restrict__ whvT, const float* __restrict__ bhv,
    bf16_t* __restrict__ concat)
{
    __shared__ bf16_t lds[4 * 4608];
    const int t = threadIdx.x, w = t >> 6, lane = t & 63;
    const int lane15 = lane & 15, quad = lane >> 4;
    bf16_t* Qh  = lds + w * 4608;   // [16][64]
    bf16_t* Kh  = Qh + 1024;        // [16][64]
    bf16_t* VhT = Kh + 1024;        // [64][32] (k-padded)
    bf16_t* P16 = VhT + 2048;       // [16][32] (k-padded)
    const int p = blockIdx.x * 4 + w;

    bf16x8 z8 = {(bf16_t)0.f, (bf16_t)0.f, (bf16_t)0.f, (bf16_t)0.f,
                 (bf16_t)0.f, (bf16_t)0.f, (bf16_t)0.f, (bf16_t)0.f};
    ((bf16x8*)P16)[lane] = z8;
#pragma unroll
    for (int i = 0; i < 4; i++) ((bf16x8*)VhT)[i * 64 + lane] = z8;

    const bf16_t* hb = attn + ((size_t)p * 16 + lane15) * 64;
    bf16x8 ha0 = *(const bf16x8*)(hb + quad * 8);
    bf16x8 ha1 = *(const bf16x8*)(hb + 32 + quad * 8);

    const bf16_t* Wt[3] = {whqT, whkT, whvT};
    const float*  Bb[3] = {bhq, bhk, bhv};
    f32x4 zf = {0.f, 0.f, 0.f, 0.f};
#pragma unroll
    for (int m3 = 0; m3 < 3; m3++) {
#pragma unroll
        for (int nf = 0; nf < 4; nf++) {
            f32x4 acc = zf;
            bf16x8 wb0 = *(const bf16x8*)(Wt[m3] + (nf * 16 + lane15) * 64 + quad * 8);
            bf16x8 wb1 = *(const bf16x8*)(Wt[m3] + (nf * 16 + lane15) * 64 + 32 + quad * 8);
            acc = __builtin_amdgcn_mfma_f32_16x16x32_bf16(ha0, wb0, acc, 0, 0, 0);
            acc = __builtin_amdgcn_mfma_f32_16x16x32_bf16(ha1, wb1, acc, 0, 0, 0);
            float bias = Bb[m3][nf * 16 + lane15];
#pragma unroll
            for (int r = 0; r < 4; r++) {
                float v = acc[r] + bias;
                if (m3 == 0) v *= 0.125f;   // fold inter scale into Qh (exact)
                if (m3 == 2) VhT[(nf * 16 + lane15) * 32 + quad * 4 + r] = (bf16_t)v;
                else if (m3 == 0) Qh[(quad * 4 + r) * 64 + nf * 16 + lane15] = (bf16_t)v;
                else Kh[(quad * 4 + r) * 64 + nf * 16 + lane15] = (bf16_t)v;
            }
        }
    }
    __syncthreads();

    bf16x8 qa0 = *(const bf16x8*)(Qh + lane15 * 64 + quad * 8);
    bf16x8 qa1 = *(const bf16x8*)(Qh + lane15 * 64 + 32 + quad * 8);
    bf16x8 kb0 = *(const bf16x8*)(Kh + lane15 * 64 + quad * 8);
    bf16x8 kb1 = *(const bf16x8*)(Kh + lane15 * 64 + 32 + quad * 8);
    f32x4 s = zf;
    s = __builtin_amdgcn_mfma_f32_16x16x32_bf16(qa0, kb0, s, 0, 0, 0);
    s = __builtin_amdgcn_mfma_f32_16x16x32_bf16(qa1, kb1, s, 0, 0, 0);
#pragma unroll
    for (int r = 0; r < 4; r++) {
        float v = s[r];
        float mx = v;
        mx = fmaxf(mx, __shfl_xor(mx, 1));
        mx = fmaxf(mx, __shfl_xor(mx, 2));
        mx = fmaxf(mx, __shfl_xor(mx, 4));
        mx = fmaxf(mx, __shfl_xor(mx, 8));
        float pv = __expf(v - mx);
        float sm = pv;
        sm += __shfl_xor(sm, 1);
        sm += __shfl_xor(sm, 2);
        sm += __shfl_xor(sm, 4);
        sm += __shfl_xor(sm, 8);
        P16[(quad * 4 + r) * 32 + lane15] = (bf16_t)(pv / sm);
    }
    __syncthreads();

    bf16x8 pa = *(const bf16x8*)(P16 + lane15 * 32 + quad * 8);
    bf16_t* outp = concat + (size_t)p * 1024;
#pragma unroll
    for (int df = 0; df < 4; df++) {
        bf16x8 vb = *(const bf16x8*)(VhT + (df * 16 + lane15) * 32 + quad * 8);
        f32x4 mix = zf;
        mix = __builtin_amdgcn_mfma_f32_16x16x32_bf16(pa, vb, mix, 0, 0, 0);
#pragma unroll
        for (int r = 0; r < 4; r++)
            outp[(quad * 4 + r) * 64 + df * 16 + lane15] = (bf16_t)mix[r];
    }
}

// ---------------------------------------------------------------------------
extern "C" void kernel_launch(void* const* d_in, const int* in_sizes, int n_in,
                              void* d_out, int out_size, void* d_ws, size_t ws_size,
                              hipStream_t stream)
{
    const float* q_in = (const float*)d_in[0];
    const float* k_in = (const float*)d_in[1];
    const float* v_in = (const float*)d_in[2];
    const int*   mask = (const int*)d_in[3];
    const float* wq = (const float*)d_in[4];
    const float* bq = (const float*)d_in[5];
    const float* wk = (const float*)d_in[6];
    const float* bk = (const float*)d_in[7];
    const float* wv = (const float*)d_in[8];
    const float* bv = (const float*)d_in[9];
    const float* wo = (const float*)d_in[10];
    const float* bo = (const float*)d_in[11];
    const float* whq = (const float*)d_in[12];
    const float* bhq = (const float*)d_in[13];
    const float* whk = (const float*)d_in[14];
    const float* bhk = (const float*)d_in[15];
    const float* whv = (const float*)d_in[16];
    const float* bhv = (const float*)d_in[17];
    float* out = (float*)d_out;         // [4096][1024] f32 = 16 MB

    char* ws = (char*)d_ws;
    bf16_t* qkvb  = (bf16_t*)ws;                       // 24 MB: Q|K|Vt
    bf16_t* concat = qkvb;                             // Q region, post-flash
    bf16_t* woT   = (bf16_t*)(ws + 8u * 1024 * 1024);  // K region, post-flash
    bf16_t* whqT  = (bf16_t*)(ws + 10u * 1024 * 1024);
    bf16_t* whkT  = whqT + 4096;
    bf16_t* whvT  = whqT + 8192;
    bf16_t* abf   = (bf16_t*)(ws + 24u * 1024 * 1024); // 24 MB bf16 A (if ws permits)
    bf16_t* attnb = (bf16_t*)d_out;                    // 8 MB bf16 in d_out
    bf16_t* wqkvT = (bf16_t*)((char*)d_out + 8u * 1024 * 1024);
    int*    flags = (int*)((char*)d_out + 14u * 1024 * 1024);

    const bool bigws = (ws_size >= 48u * 1024 * 1024);

    prep1_kernel<<<bigws ? 4352 : 2816, 256, 0, stream>>>(
        mask, flags, wq, wk, wv, wqkvT, q_in, k_in, v_in, abf);
    if (bigws)
        gemm_qkv_t<true><<<dim3(32, 8, 3), 256, 0, stream>>>(
            q_in, k_in, v_in, abf, wqkvT, bq, bk, bv, qkvb);
    else
        gemm_qkv_t<false><<<dim3(32, 8, 3), 256, 0, stream>>>(
            q_in, k_in, v_in, abf, wqkvT, bq, bk, bv, qkvb);
    flash_kernel<<<dim3(32, 16), 256, 0, stream>>>(qkvb, mask, flags, attnb);
    prep2_kernel<<<259, 256, 0, stream>>>(wo, woT, whq, whk, whv, whqT, whkT, whvT);
    interhead_kernel<<<1024, 256, 0, stream>>>(attnb, whqT, bhq, whkT, bhk, whvT, bhv, concat);
    gemm_out_kernel<<<dim3(32, 16), 256, 0, stream>>>(concat, woT, bo, out);
    (void)in_sizes; (void)n_in; (void)out_size; (void)ws_size;
}